// Round 6
// baseline (199.046 us; speedup 1.0000x reference)
//
#include <hip/hip_runtime.h>
#include <hip/hip_bf16.h>

typedef unsigned short u16;
typedef unsigned int u32;
typedef __attribute__((ext_vector_type(8))) short short8;
typedef __attribute__((ext_vector_type(4))) short short4v;
typedef __attribute__((ext_vector_type(4))) float f32x4;

typedef unsigned int __attribute__((address_space(1))) as1_u32;
typedef unsigned int __attribute__((address_space(3))) as3_u32;

__device__ __forceinline__ void gload16(const void* g, void* l) {
    __builtin_amdgcn_global_load_lds((const as1_u32*)g, (as3_u32*)l, 16, 0, 0);
}

// round-to-nearest-even f32 -> bf16 bits (finite inputs only)
__device__ __forceinline__ u16 f2b(float f) {
    union { float f; unsigned u; } v; v.f = f;
    unsigned r = v.u + 0x7fffu + ((v.u >> 16) & 1u);
    return (u16)(r >> 16);
}

__device__ __forceinline__ f32x4 mfma32(short8 a, short8 b, f32x4 c) {
    return __builtin_amdgcn_mfma_f32_16x16x32_bf16(a, b, c, 0, 0, 0);
}
// k=16 bf16 MFMA via inline asm (ISA-listed; operands dependency-tracked)
__device__ __forceinline__ f32x4 mfma16(short4v a, short4v b, f32x4 c) {
    asm("v_mfma_f32_16x16x16_bf16 %0, %1, %2, %0" : "+v"(c) : "v"(a), "v"(b));
    return c;
}

// ---------------------------------------------------------------------------
// transpose + cast fp32 [R][C] -> bf16 [C][R]
// ---------------------------------------------------------------------------
__global__ void transpose_cast(const float* __restrict__ src,
                               u16* __restrict__ dst, int R, int C) {
    __shared__ float tile[32][33];
    const int c0 = blockIdx.x * 32, r0 = blockIdx.y * 32;
    const int tx = threadIdx.x, ty = threadIdx.y;   // block (32,8)
#pragma unroll
    for (int i = ty; i < 32; i += 8)
        tile[i][tx] = src[(size_t)(r0 + i) * C + c0 + tx];
    __syncthreads();
#pragma unroll
    for (int i = ty; i < 32; i += 8)
        dst[(size_t)(c0 + i) * R + r0 + tx] = f2b(tile[tx][i]);
}

// ---------------------------------------------------------------------------
// bf16 transpose per batch: src [8][2048][256] -> dst [8][256][2048]
// ---------------------------------------------------------------------------
__global__ void transpose_bf16(const u16* __restrict__ src, u16* __restrict__ dst) {
    __shared__ u16 t[32][33];
    const int b = blockIdx.z;
    const int n0 = blockIdx.x * 32, d0 = blockIdx.y * 32;
    const int tx = threadIdx.x, ty = threadIdx.y;   // block (32,8)
    const u16* s = src + (size_t)b * (2048 * 256);
    u16* d = dst + (size_t)b * (2048 * 256);
#pragma unroll
    for (int i = ty; i < 32; i += 8)
        t[i][tx] = s[(size_t)(n0 + i) * 256 + d0 + tx];
    __syncthreads();
#pragma unroll
    for (int i = ty; i < 32; i += 8)
        d[(size_t)(d0 + i) * 2048 + n0 + tx] = t[tx][i];
}

// ---------------------------------------------------------------------------
// LayerNorm: fp32 [rows][256] -> bf16 [rows][256]; one wave per row
// ---------------------------------------------------------------------------
__global__ __launch_bounds__(256) void ln_kernel(
    const float* __restrict__ x, const float* __restrict__ g,
    const float* __restrict__ be, u16* __restrict__ out) {
    const int lane = threadIdx.x & 63;
    const size_t row = (size_t)blockIdx.x * 4 + (threadIdx.x >> 6);
    const float4 v = *((const float4*)(x + row * 256) + lane);
    float s  = v.x + v.y + v.z + v.w;
    float s2 = v.x * v.x + v.y * v.y + v.z * v.z + v.w * v.w;
#pragma unroll
    for (int m = 1; m < 64; m <<= 1) {
        s  += __shfl_xor(s, m);
        s2 += __shfl_xor(s2, m);
    }
    const float mean = s * (1.0f / 256.0f);
    const float var  = s2 * (1.0f / 256.0f) - mean * mean;
    const float rstd = rsqrtf(var + 1e-5f);
    const float4 gv = *((const float4*)g + lane);
    const float4 bv = *((const float4*)be + lane);
    ushort4 o;
    o.x = f2b((v.x - mean) * rstd * gv.x + bv.x);
    o.y = f2b((v.y - mean) * rstd * gv.y + bv.y);
    o.z = f2b((v.z - mean) * rstd * gv.z + bv.z);
    o.w = f2b((v.w - mean) * rstd * gv.w + bv.w);
    *((ushort4*)(out + row * 256) + lane) = o;
}

// ---------------------------------------------------------------------------
// Flash attention, Q=K=V=h (bf16), D=256, N=2048.
// Block: 64 q-rows, 8 waves (512 thr). Wave w: qhalf = w>>2 (32 q, 2 subtiles
// in regs), kv-quarter = w&3 (16 kv of each 64-tile).
// Swapped QK^T (mfma(K,Q)) -> S^T C-layout == PV A-layout for k=16 MFMA:
// P never touches LDS. Per-wave (m,l,O) partials; 4-way kv merge at end.
// LDS: 2 x 64KB staging (K [64][512B] + V^T [256][128B], XOR-swizzled)
//      + ml table 2KB @131072. Merge reuses staging area.
// ---------------------------------------------------------------------------
#define ATTN_LDS_BYTES (2*65536 + 2048)   // 133120

__global__ __launch_bounds__(512, 2) void attn_kernel(
    const u16* __restrict__ h, const u16* __restrict__ hT,
    const float* __restrict__ x, float* __restrict__ xmid) {
    extern __shared__ char smem[];
    const int tid  = threadIdx.x;
    const int w    = tid >> 6;
    const int lane = tid & 63;
    const int grp  = lane >> 4;
    const int l16  = lane & 15;
    const int kvq  = w & 3;
    const int qh   = w >> 2;
    const int bid  = blockIdx.x;
    const int b    = bid & 7;          // batch -> XCD pinning
    const int q0   = (bid >> 3) * 64;

    const u16* hb = h + (size_t)b * (2048 * 256);
    const char* hbB = (const char*)hb;
    const char* hTB = (const char*)(hT + (size_t)b * (2048 * 256));

    // Q fragments for 2 subtiles (B-operand of swapped QK)
    short8 qf[2][8];
#pragma unroll
    for (int st = 0; st < 2; ++st) {
        const u16* qp = hb + (size_t)(q0 + qh * 32 + st * 16 + l16) * 256 + grp * 8;
#pragma unroll
        for (int kk = 0; kk < 8; ++kk) qf[st][kk] = *(const short8*)(qp + kk * 32);
    }

    f32x4 oacc[2][16];
#pragma unroll
    for (int st = 0; st < 2; ++st)
#pragma unroll
        for (int dt = 0; dt < 16; ++dt) oacc[st][dt] = (f32x4){0.f, 0.f, 0.f, 0.f};
    float m_run[2] = {-1e30f, -1e30f};
    float l_run[2] = {0.f, 0.f};

    // staging source bases (pre-swizzled global; LDS written linearly)
    const char* gK0 = hbB + ((size_t)(tid >> 5) << 9)
                          + (((tid & 31) ^ ((tid >> 5) & 7)) << 4);
    const char* gV0 = hTB + ((size_t)(tid >> 3) << 12)
                          + (((tid & 7) ^ ((tid >> 3) & 7)) << 4);

    {   // prologue: tile 0 -> buf0
        char* lK = smem + w * 1024;
        char* lV = smem + 32768 + w * 1024;
#pragma unroll
        for (int it = 0; it < 4; ++it) gload16(gK0 + (size_t)it * 8192, lK + it * 8192);
#pragma unroll
        for (int it = 0; it < 4; ++it) gload16(gV0 + (size_t)it * 262144, lV + it * 8192);
    }
    __syncthreads();

    for (int kt = 0; kt < 32; ++kt) {
        const int cur = kt & 1;
        if (kt < 31) {
            char* lK = smem + (cur ^ 1) * 65536 + w * 1024;
            char* lV = smem + (cur ^ 1) * 65536 + 32768 + w * 1024;
            const char* gK = gK0 + (size_t)(kt + 1) * 32768;
            const char* gV = gV0 + (size_t)(kt + 1) * 128;
#pragma unroll
            for (int it = 0; it < 4; ++it) gload16(gK + (size_t)it * 8192, lK + it * 8192);
#pragma unroll
            for (int it = 0; it < 4; ++it) gload16(gV + (size_t)it * 262144, lV + it * 8192);
        }
        const char* KB = smem + cur * 65536;
        const char* VB = KB + 32768;

        // --- S^T = mfma(K, Q): D[kv = grp*4+r][q = l16], one K-read feeds 2 st
        f32x4 sacc[2] = {(f32x4){0.f,0.f,0.f,0.f}, (f32x4){0.f,0.f,0.f,0.f}};
        const char* rb = KB + ((kvq * 16 + l16) << 9);
#pragma unroll
        for (int kk = 0; kk < 8; ++kk) {
            const int c = grp + 4 * kk;
            const int swz = (c & ~7) | ((c ^ l16) & 7);
            const short8 kf = *(const short8*)(rb + (swz << 4));
            sacc[0] = mfma32(kf, qf[0][kk], sacc[0]);
            sacc[1] = mfma32(kf, qf[1][kk], sacc[1]);
        }

        // --- online softmax (per-lane row q = l16; reduce over 4 grps) ---
        short4v pa[2];
#pragma unroll
        for (int st = 0; st < 2; ++st) {
            float p0 = sacc[st][0] * 0.0625f, p1 = sacc[st][1] * 0.0625f;
            float p2 = sacc[st][2] * 0.0625f, p3 = sacc[st][3] * 0.0625f;
            float mx = fmaxf(fmaxf(p0, p1), fmaxf(p2, p3));
            mx = fmaxf(mx, __shfl_xor(mx, 16));
            mx = fmaxf(mx, __shfl_xor(mx, 32));
            if (__any(mx > m_run[st] + 8.f)) {   // defer-max (T13)
                const float mnew  = fmaxf(m_run[st], mx);
                const float alpha = __expf(m_run[st] - mnew);
                m_run[st] = mnew;
                l_run[st] *= alpha;
                float ar[4];
#pragma unroll
                for (int r = 0; r < 4; ++r) ar[r] = __shfl(alpha, grp * 4 + r);
#pragma unroll
                for (int dt = 0; dt < 16; ++dt)
#pragma unroll
                    for (int r = 0; r < 4; ++r) oacc[st][dt][r] *= ar[r];
            }
            const float e0 = __expf(p0 - m_run[st]);
            const float e1 = __expf(p1 - m_run[st]);
            const float e2 = __expf(p2 - m_run[st]);
            const float e3 = __expf(p3 - m_run[st]);
            float lt = e0 + e1 + e2 + e3;
            lt += __shfl_xor(lt, 16);
            lt += __shfl_xor(lt, 32);
            l_run[st] += lt;
            pa[st] = (short4v){(short)f2b(e0), (short)f2b(e1),
                               (short)f2b(e2), (short)f2b(e3)};
        }

        // --- O += P V (k=16): V^T b64 reads, bank-floor swizzle ---
        const char* vbase = VB + l16 * 128
                          + (((kvq * 2 + (grp >> 1)) ^ (l16 & 7)) << 4)
                          + (grp & 1) * 8;
#pragma unroll
        for (int dt = 0; dt < 16; ++dt) {
            const short4v bv = *(const short4v*)(vbase + dt * 2048);
            oacc[0][dt] = mfma16(pa[0], bv, oacc[0][dt]);
            oacc[1][dt] = mfma16(pa[1], bv, oacc[1][dt]);
        }
        __syncthreads();
    }

    // ==== merge: 4-way over kv-quarters (per qhalf), 2 d-rounds ====
    float2* ml = (float2*)(smem + 131072);      // [8 waves][32 q_local]
    if (lane < 16) {
        float2 t0; t0.x = m_run[0]; t0.y = l_run[0];
        float2 t1; t1.x = m_run[1]; t1.y = l_run[1];
        ml[w * 32 + lane]      = t0;
        ml[w * 32 + 16 + lane] = t1;
    }
    const int dq = w & 3;
    float an[2][4][4];
    const float* xb = x + (size_t)b * (2048 * 256);
    float* ob = xmid + (size_t)b * (2048 * 256);
#pragma unroll
    for (int rnd = 0; rnd < 2; ++rnd) {
        char* wb = smem + w * 16384;
#pragma unroll
        for (int st = 0; st < 2; ++st)
#pragma unroll
            for (int k = 0; k < 8; ++k)
                *(f32x4*)(wb + ((st * 8 + k) * 64 + lane) * 16) = oacc[st][rnd * 8 + k];
        __syncthreads();
        if (rnd == 0) {   // per-q merge scales (once)
#pragma unroll
            for (int st = 0; st < 2; ++st)
#pragma unroll
                for (int rr = 0; rr < 4; ++rr) {
                    const int q = st * 16 + grp * 4 + rr;
                    float mv[4], lv[4];
#pragma unroll
                    for (int kq = 0; kq < 4; ++kq) {
                        const float2 t = ml[(qh * 4 + kq) * 32 + q];
                        mv[kq] = t.x; lv[kq] = t.y;
                    }
                    const float M = fmaxf(fmaxf(mv[0], mv[1]), fmaxf(mv[2], mv[3]));
                    float a[4], L = 0.f;
#pragma unroll
                    for (int kq = 0; kq < 4; ++kq) {
                        a[kq] = __expf(mv[kq] - M);
                        L += a[kq] * lv[kq];
                    }
                    const float inv = 1.0f / L;
#pragma unroll
                    for (int kq = 0; kq < 4; ++kq) an[st][rr][kq] = a[kq] * inv;
                }
        }
#pragma unroll
        for (int j = 0; j < 2; ++j) {
            const int dtg = rnd * 8 + dq * 2 + j;
#pragma unroll
            for (int st = 0; st < 2; ++st) {
                f32x4 acc = (f32x4){0.f, 0.f, 0.f, 0.f};
#pragma unroll
                for (int kq = 0; kq < 4; ++kq) {
                    const f32x4 ch = *(const f32x4*)(smem + (qh * 4 + kq) * 16384
                                     + ((st * 8 + dq * 2 + j) * 64 + lane) * 16);
#pragma unroll
                    for (int rr = 0; rr < 4; ++rr) acc[rr] += an[st][rr][kq] * ch[rr];
                }
                const int col = dtg * 16 + l16;
#pragma unroll
                for (int rr = 0; rr < 4; ++rr) {
                    const int row = q0 + qh * 32 + st * 16 + grp * 4 + rr;
                    const size_t idx = (size_t)row * 256 + col;
                    ob[idx] = xb[idx] + acc[rr];
                }
            }
        }
        if (rnd == 0) __syncthreads();
    }
}

// ---------------------------------------------------------------------------
// Fused FFN: out = xmid + relu(h2 @ w1 + b1) @ w2 + b2   (in-place on xmid)
// Block: 64 tokens, 8 waves. Wave w: tokhalf = w>>2 (32 tok in regs),
// hid-quarter = w&3 (16 of each 64-hid chunk). Swapped gemm1 -> A1 in regs ->
// gemm2 k=16 MFMA. 4-way plain-sum merge.
// ---------------------------------------------------------------------------
#define FFN_LDS_BYTES (2*65536 + 4096)    // 135168

__global__ __launch_bounds__(512, 2) void ffn_kernel(
    const u16* __restrict__ h2, const u16* __restrict__ w1t,
    const u16* __restrict__ w2t, const float* __restrict__ b1,
    const float* __restrict__ b2, float* __restrict__ xmid) {
    extern __shared__ char smem[];
    const int tid  = threadIdx.x;
    const int w    = tid >> 6;
    const int lane = tid & 63;
    const int grp  = lane >> 4;
    const int l16  = lane & 15;
    const int hq   = w & 3;
    const int th   = w >> 2;
    const int t0   = blockIdx.x * 64;
    char* b1lds = smem + 131072;

    short8 af[2][8];
#pragma unroll
    for (int st = 0; st < 2; ++st) {
        const u16* ap = h2 + (size_t)(t0 + th * 32 + st * 16 + l16) * 256 + grp * 8;
#pragma unroll
        for (int kk = 0; kk < 8; ++kk) af[st][kk] = *(const short8*)(ap + kk * 32);
    }

    f32x4 oacc[2][16];
#pragma unroll
    for (int st = 0; st < 2; ++st)
#pragma unroll
        for (int dt = 0; dt < 16; ++dt) oacc[st][dt] = (f32x4){0.f, 0.f, 0.f, 0.f};

    const char* g10 = (const char*)w1t + ((size_t)(tid >> 5) << 9)
                                       + (((tid & 31) ^ ((tid >> 5) & 7)) << 4);
    const char* g20 = (const char*)w2t + ((size_t)(tid >> 3) << 11)
                                       + (((tid & 7) ^ ((tid >> 3) & 7)) << 4);

    {   // prologue: chunk 0 -> buf0, b1 -> LDS
        char* l1 = smem + w * 1024;
        char* l2 = smem + 32768 + w * 1024;
#pragma unroll
        for (int it = 0; it < 4; ++it) gload16(g10 + (size_t)it * 8192, l1 + it * 8192);
#pragma unroll
        for (int it = 0; it < 4; ++it) gload16(g20 + (size_t)it * 131072, l2 + it * 8192);
        if (tid < 256) gload16((const char*)b1 + tid * 16, b1lds + tid * 16);
    }
    __syncthreads();

    for (int hc = 0; hc < 16; ++hc) {
        const int cur = hc & 1;
        if (hc < 15) {
            char* l1 = smem + (cur ^ 1) * 65536 + w * 1024;
            char* l2 = smem + (cur ^ 1) * 65536 + 32768 + w * 1024;
            const char* g1 = g10 + (size_t)(hc + 1) * 32768;
            const char* g2 = g20 + (size_t)(hc + 1) * 128;
#pragma unroll
            for (int it = 0; it < 4; ++it) gload16(g1 + (size_t)it * 8192, l1 + it * 8192);
#pragma unroll
            for (int it = 0; it < 4; ++it) gload16(g2 + (size_t)it * 131072, l2 + it * 8192);
        }
        const char* W1B = smem + cur * 65536;
        const char* W2B = W1B + 32768;

        // gemm1 swapped: D[hid = grp*4+r][tok = l16]; one W1-read feeds 2 st
        f32x4 sacc[2] = {(f32x4){0.f,0.f,0.f,0.f}, (f32x4){0.f,0.f,0.f,0.f}};
        const char* rb = W1B + ((hq * 16 + l16) << 9);
#pragma unroll
        for (int kk = 0; kk < 8; ++kk) {
            const int c = grp + 4 * kk;
            const int swz = (c & ~7) | ((c ^ l16) & 7);
            const short8 wf = *(const short8*)(rb + (swz << 4));
            sacc[0] = mfma32(wf, af[0][kk], sacc[0]);
            sacc[1] = mfma32(wf, af[1][kk], sacc[1]);
        }

        // bias + relu -> A1 fragments in regs
        const f32x4 bb = *(const f32x4*)(b1lds + (hc * 64 + hq * 16 + grp * 4) * 4);
        short4v pa[2];
#pragma unroll
        for (int st = 0; st < 2; ++st) {
            const float v0 = fmaxf(sacc[st][0] + bb[0], 0.f);
            const float v1 = fmaxf(sacc[st][1] + bb[1], 0.f);
            const float v2 = fmaxf(sacc[st][2] + bb[2], 0.f);
            const float v3 = fmaxf(sacc[st][3] + bb[3], 0.f);
            pa[st] = (short4v){(short)f2b(v0), (short)f2b(v1),
                               (short)f2b(v2), (short)f2b(v3)};
        }

        // gemm2 (k=16): O += A1 @ W2[chunk]
        const char* vbase = W2B + l16 * 128
                          + (((hq * 2 + (grp >> 1)) ^ (l16 & 7)) << 4)
                          + (grp & 1) * 8;
#pragma unroll
        for (int dt = 0; dt < 16; ++dt) {
            const short4v bv = *(const short4v*)(vbase + dt * 2048);
            oacc[0][dt] = mfma16(pa[0], bv, oacc[0][dt]);
            oacc[1][dt] = mfma16(pa[1], bv, oacc[1][dt]);
        }
        __syncthreads();
    }

    // ==== merge: plain 4-way sum over hid-quarters, 2 d-rounds ====
    const int dq = w & 3;
#pragma unroll
    for (int rnd = 0; rnd < 2; ++rnd) {
        char* wb = smem + w * 16384;
#pragma unroll
        for (int st = 0; st < 2; ++st)
#pragma unroll
            for (int k = 0; k < 8; ++k)
                *(f32x4*)(wb + ((st * 8 + k) * 64 + lane) * 16) = oacc[st][rnd * 8 + k];
        __syncthreads();
#pragma unroll
        for (int j = 0; j < 2; ++j) {
            const int dtg = rnd * 8 + dq * 2 + j;
            const int col = dtg * 16 + l16;
            const float b2v = b2[col];
#pragma unroll
            for (int st = 0; st < 2; ++st) {
                f32x4 acc = (f32x4){0.f, 0.f, 0.f, 0.f};
#pragma unroll
                for (int kq = 0; kq < 4; ++kq) {
                    const f32x4 ch = *(const f32x4*)(smem + (th * 4 + kq) * 16384
                                     + ((st * 8 + dq * 2 + j) * 64 + lane) * 16);
#pragma unroll
                    for (int rr = 0; rr < 4; ++rr) acc[rr] += ch[rr];
                }
#pragma unroll
                for (int rr = 0; rr < 4; ++rr) {
                    const int row = t0 + th * 32 + st * 16 + grp * 4 + rr;
                    const size_t idx = (size_t)row * 256 + col;
                    xmid[idx] = xmid[idx] + acc[rr] + b2v;
                }
            }
        }
        if (rnd == 0) __syncthreads();
    }
}

// ---------------------------------------------------------------------------
extern "C" void kernel_launch(void* const* d_in, const int* in_sizes, int n_in,
                              void* d_out, int out_size, void* d_ws, size_t ws_size,
                              hipStream_t stream) {
    (void)in_sizes; (void)n_in; (void)out_size; (void)ws_size;
    const float* x   = (const float*)d_in[0];
    const float* w1  = (const float*)d_in[1];
    const float* b1  = (const float*)d_in[2];
    const float* w2  = (const float*)d_in[3];
    const float* b2  = (const float*)d_in[4];
    const float* g1  = (const float*)d_in[5];
    const float* be1 = (const float*)d_in[6];
    const float* g2  = (const float*)d_in[7];
    const float* be2 = (const float*)d_in[8];
    float* out = (float*)d_out;

    char* ws = (char*)d_ws;
    u16* h   = (u16*)ws;                        // 8 MiB (LN1 out; later LN2 out)
    u16* hT  = (u16*)(ws + 8388608);            // 8 MiB transposed h
    u16* w1t = (u16*)(ws + 16777216);           // [1024][256] bf16
    u16* w2t = (u16*)(ws + 17301504);           // [256][1024] bf16

    hipFuncSetAttribute((const void*)attn_kernel,
                        hipFuncAttributeMaxDynamicSharedMemorySize, ATTN_LDS_BYTES);
    hipFuncSetAttribute((const void*)ffn_kernel,
                        hipFuncAttributeMaxDynamicSharedMemorySize, FFN_LDS_BYTES);

    // weight transposes
    transpose_cast<<<dim3(32, 8), dim3(32, 8), 0, stream>>>(w1, w1t, 256, 1024);
    transpose_cast<<<dim3(8, 32), dim3(32, 8), 0, stream>>>(w2, w2t, 1024, 256);

    // sublayer 1
    ln_kernel<<<4096, 256, 0, stream>>>(x, g1, be1, h);
    transpose_bf16<<<dim3(64, 8, 8), dim3(32, 8), 0, stream>>>(h, hT);
    attn_kernel<<<256, 512, ATTN_LDS_BYTES, stream>>>(h, hT, x, out);

    // sublayer 2 (h buffer reused for LN2 output)
    ln_kernel<<<4096, 256, 0, stream>>>(out, g2, be2, h);
    ffn_kernel<<<256, 512, FFN_LDS_BYTES, stream>>>(h, w1t, w2t, b1, b2, out);
}